// Round 5
// baseline (1020.990 us; speedup 1.0000x reference)
//
#include <hip/hip_runtime.h>
#include <hip/hip_bf16.h>
#include <math.h>

// ConformHopfieldBatch: B=4 S=2048 IN=64 D=128 HID=400 H=4 K=20 NQ=18
// softmax monotone -> top_k(assoc) == top_k(raw scores). bf16-hi MFMA
// PREFILTER -> 80 candidates/row; exact fp32 RESCORE selects true top-20
// (R2 lesson: selection needs fp32-exact scores).
// R4 postmortem: K-loop was latency-bound: 128-VGPR prefetch dbuf spilled
// (VGPR_Count=128 < demand ~200) and per-mt __syncthreads drains vmcnt(0).
// R5: MFMA operands SWAPPED (A=K-frag, B=Q-frag) so each lane owns one
// q-row's scores in its accumulator -> no LDS score tile, ZERO barriers in
// the K-loop, no dbuf. Fragment loads identical to R4 (verified mapping).
// Grid XCD-swizzled: 32 blocks sharing one (b,h) slab -> same XCD (L2 local).
// k_mlp: xa overlapped into hB (LDS 51.2KB -> 3 blocks/CU) + 1-chunk-ahead
// weight prefetch (FMA i-order unchanged -> bit-identical enc).

#define SS 2048

typedef short short8v __attribute__((ext_vector_type(8)));
typedef float float4v __attribute__((ext_vector_type(4)));

__constant__ float c_alphas[18] = {0.05f,0.06f,0.08f,0.1f,0.12f,0.14f,0.15f,0.17f,
                                   0.19f,0.2f,0.21f,0.23f,0.25f,0.3f,0.35f,0.38f,0.4f,0.45f};

// output flat offsets (return-order concat)
#define OFF_Y      1
#define OFF_YPRED  32769
#define OFF_YLOW   65537ll
#define OFF_YHIGH  655361ll
#define OFF_ERR    1245185ll
#define OFF_QLOW   1253377ll
#define OFF_QHIGH  1843201ll

__device__ inline short f2bf_s(float f) {
    __hip_bfloat16 h = __float2bfloat16(f);
    return __builtin_bit_cast(short, h);
}
// monotone fp32 -> u32 map (order-preserving)
__device__ inline unsigned mono(float f) {
    unsigned u = __builtin_bit_cast(unsigned, f);
    return (u & 0x80000000u) ? ~u : (u | 0x80000000u);
}

// ---------------------------------------------------------------------------
// Kernel A: fused MLP(64->400->400->400->128) + LayerNorm + projection(128->512)
// 16 rows/block, 256 threads. blocks 0..511: true->q (fp32); 512..1023: sim->k
// (fp32 + bf16-hi). Head-major layout [(b*4+h)][s][128].
// xa shares hB storage (input dead after layer 1) -> LDS 51.2KB, 3 blocks/CU.
// Weight loads pipelined one chunk ahead; FMA order over i preserved exactly.
// ---------------------------------------------------------------------------
__global__ __launch_bounds__(256) void k_mlp(
    const float* __restrict__ Xt, const float* __restrict__ Xs,
    const float* __restrict__ W1, const float* __restrict__ b1,
    const float* __restrict__ W2, const float* __restrict__ b2,
    const float* __restrict__ W3, const float* __restrict__ b3,
    const float* __restrict__ W4, const float* __restrict__ b4,
    const float* __restrict__ Wq, const float* __restrict__ bq,
    const float* __restrict__ Wk, const float* __restrict__ bk,
    const float* __restrict__ g_q, const float* __restrict__ beta_q,
    const float* __restrict__ g_k, const float* __restrict__ beta_k,
    float* __restrict__ qf, float* __restrict__ kf,
    __hip_bfloat16* __restrict__ khi)
{
    __shared__ float hA[16*400];   // 25.6KB
    __shared__ float hB[16*400];   // 25.6KB; first 1024 floats double as xa
    float* xa = hB;

    const int tid  = threadIdx.x;
    const int half = (blockIdx.x >= 512) ? 1 : 0;
    const int row0 = (blockIdx.x & 511) * 16;
    const float* X = half ? Xs : Xt;

    {
        const float4* src = (const float4*)(X + (size_t)row0 * 64);
        ((float4*)xa)[tid] = src[tid];
    }
    __syncthreads();

    // ---- layer 1: 64 -> 400 (relu), xa(=hB) -> hA ----
    {
        const int j0 = tid, j1 = tid + 256;
        const bool v1 = (j1 < 400);
        const int j1m = v1 ? j1 : j0;
        float acc0[16], acc1[16];
        #pragma unroll
        for (int r = 0; r < 16; ++r) { acc0[r] = 0.f; acc1[r] = 0.f; }
        float w0c[4], w1c[4];
        #pragma unroll
        for (int u = 0; u < 4; ++u) { w0c[u] = W1[u*400 + j0]; w1c[u] = W1[u*400 + j1m]; }
        #pragma unroll 4
        for (int i = 0; i < 64; i += 4) {
            float w0n[4], w1n[4];
            const int ip = (i + 4 < 64) ? (i + 4) : i;
            #pragma unroll
            for (int u = 0; u < 4; ++u) { w0n[u] = W1[(ip+u)*400 + j0]; w1n[u] = W1[(ip+u)*400 + j1m]; }
            #pragma unroll
            for (int r = 0; r < 16; ++r) {
                const float4 xv = *(const float4*)&xa[r*64 + i];
                acc0[r] = fmaf(xv.x, w0c[0], acc0[r]); acc1[r] = fmaf(xv.x, w1c[0], acc1[r]);
                acc0[r] = fmaf(xv.y, w0c[1], acc0[r]); acc1[r] = fmaf(xv.y, w1c[1], acc1[r]);
                acc0[r] = fmaf(xv.z, w0c[2], acc0[r]); acc1[r] = fmaf(xv.z, w1c[2], acc1[r]);
                acc0[r] = fmaf(xv.w, w0c[3], acc0[r]); acc1[r] = fmaf(xv.w, w1c[3], acc1[r]);
            }
            #pragma unroll
            for (int u = 0; u < 4; ++u) { w0c[u] = w0n[u]; w1c[u] = w1n[u]; }
        }
        const float bb0 = b1[j0], bb1 = b1[j1m];
        __syncthreads();   // xa reads done before hA... (hA write-only here; barrier orders vs hB overwrite next layer)
        #pragma unroll
        for (int r = 0; r < 16; ++r) {
            hA[r*400 + j0] = fmaxf(acc0[r] + bb0, 0.f);
            if (v1) hA[r*400 + j1] = fmaxf(acc1[r] + bb1, 0.f);
        }
    }
    __syncthreads();

    // ---- layer 2: 400 -> 400 (relu), hA -> hB ----
    {
        const int j0 = tid, j1 = tid + 256;
        const bool v1 = (j1 < 400);
        const int j1m = v1 ? j1 : j0;
        float acc0[16], acc1[16];
        #pragma unroll
        for (int r = 0; r < 16; ++r) { acc0[r] = 0.f; acc1[r] = 0.f; }
        float w0c[4], w1c[4];
        #pragma unroll
        for (int u = 0; u < 4; ++u) { w0c[u] = W2[u*400 + j0]; w1c[u] = W2[u*400 + j1m]; }
        #pragma unroll 4
        for (int i = 0; i < 400; i += 4) {
            float w0n[4], w1n[4];
            const int ip = (i + 4 < 400) ? (i + 4) : i;
            #pragma unroll
            for (int u = 0; u < 4; ++u) { w0n[u] = W2[(ip+u)*400 + j0]; w1n[u] = W2[(ip+u)*400 + j1m]; }
            #pragma unroll
            for (int r = 0; r < 16; ++r) {
                const float4 xv = *(const float4*)&hA[r*400 + i];
                acc0[r] = fmaf(xv.x, w0c[0], acc0[r]); acc1[r] = fmaf(xv.x, w1c[0], acc1[r]);
                acc0[r] = fmaf(xv.y, w0c[1], acc0[r]); acc1[r] = fmaf(xv.y, w1c[1], acc1[r]);
                acc0[r] = fmaf(xv.z, w0c[2], acc0[r]); acc1[r] = fmaf(xv.z, w1c[2], acc1[r]);
                acc0[r] = fmaf(xv.w, w0c[3], acc0[r]); acc1[r] = fmaf(xv.w, w1c[3], acc1[r]);
            }
            #pragma unroll
            for (int u = 0; u < 4; ++u) { w0c[u] = w0n[u]; w1c[u] = w1n[u]; }
        }
        const float bb0 = b2[j0], bb1 = b2[j1m];
        #pragma unroll
        for (int r = 0; r < 16; ++r) {
            hB[r*400 + j0] = fmaxf(acc0[r] + bb0, 0.f);
            if (v1) hB[r*400 + j1] = fmaxf(acc1[r] + bb1, 0.f);
        }
    }
    __syncthreads();

    // ---- layer 3: 400 -> 400 (relu), hB -> hA ----
    {
        const int j0 = tid, j1 = tid + 256;
        const bool v1 = (j1 < 400);
        const int j1m = v1 ? j1 : j0;
        float acc0[16], acc1[16];
        #pragma unroll
        for (int r = 0; r < 16; ++r) { acc0[r] = 0.f; acc1[r] = 0.f; }
        float w0c[4], w1c[4];
        #pragma unroll
        for (int u = 0; u < 4; ++u) { w0c[u] = W3[u*400 + j0]; w1c[u] = W3[u*400 + j1m]; }
        #pragma unroll 4
        for (int i = 0; i < 400; i += 4) {
            float w0n[4], w1n[4];
            const int ip = (i + 4 < 400) ? (i + 4) : i;
            #pragma unroll
            for (int u = 0; u < 4; ++u) { w0n[u] = W3[(ip+u)*400 + j0]; w1n[u] = W3[(ip+u)*400 + j1m]; }
            #pragma unroll
            for (int r = 0; r < 16; ++r) {
                const float4 xv = *(const float4*)&hB[r*400 + i];
                acc0[r] = fmaf(xv.x, w0c[0], acc0[r]); acc1[r] = fmaf(xv.x, w1c[0], acc1[r]);
                acc0[r] = fmaf(xv.y, w0c[1], acc0[r]); acc1[r] = fmaf(xv.y, w1c[1], acc1[r]);
                acc0[r] = fmaf(xv.z, w0c[2], acc0[r]); acc1[r] = fmaf(xv.z, w1c[2], acc1[r]);
                acc0[r] = fmaf(xv.w, w0c[3], acc0[r]); acc1[r] = fmaf(xv.w, w1c[3], acc1[r]);
            }
            #pragma unroll
            for (int u = 0; u < 4; ++u) { w0c[u] = w0n[u]; w1c[u] = w1n[u]; }
        }
        const float bb0 = b3[j0], bb1 = b3[j1m];
        #pragma unroll
        for (int r = 0; r < 16; ++r) {
            hA[r*400 + j0] = fmaxf(acc0[r] + bb0, 0.f);
            if (v1) hA[r*400 + j1] = fmaxf(acc1[r] + bb1, 0.f);
        }
    }
    __syncthreads();

    // ---- layer 4: 400 -> 128 (no relu), hA -> hB (stride 128) ----
    {
        const int j  = tid & 127;
        const int r0 = (tid >> 7) * 8;
        float acc[8];
        #pragma unroll
        for (int r = 0; r < 8; ++r) acc[r] = 0.f;
        float wc[4];
        #pragma unroll
        for (int u = 0; u < 4; ++u) wc[u] = W4[u*128 + j];
        #pragma unroll 4
        for (int i = 0; i < 400; i += 4) {
            float wn[4];
            const int ip = (i + 4 < 400) ? (i + 4) : i;
            #pragma unroll
            for (int u = 0; u < 4; ++u) wn[u] = W4[(ip+u)*128 + j];
            #pragma unroll
            for (int r = 0; r < 8; ++r) {
                const float4 xv = *(const float4*)&hA[(r0+r)*400 + i];
                acc[r] = fmaf(xv.x, wc[0], acc[r]);
                acc[r] = fmaf(xv.y, wc[1], acc[r]);
                acc[r] = fmaf(xv.z, wc[2], acc[r]);
                acc[r] = fmaf(xv.w, wc[3], acc[r]);
            }
            #pragma unroll
            for (int u = 0; u < 4; ++u) wc[u] = wn[u];
        }
        const float bb = b4[j];
        #pragma unroll
        for (int r = 0; r < 8; ++r)
            hB[(r0+r)*128 + j] = acc[r] + bb;
    }
    __syncthreads();

    // ---- LayerNorm -> hA (stride 128) ----
    {
        const float* g  = half ? g_k : g_q;
        const float* be = half ? beta_k : beta_q;
        const int lane = tid & 63;
        const int wg   = tid >> 6;
        const float gl0 = g[lane],  gl1 = g[lane+64];
        const float bl0 = be[lane], bl1 = be[lane+64];
        #pragma unroll 1
        for (int d = 0; d < 4; ++d) {
            const int r = wg*4 + d;
            const float v0 = hB[r*128 + lane];
            const float v1 = hB[r*128 + lane + 64];
            float s = v0 + v1;
            #pragma unroll
            for (int o = 32; o > 0; o >>= 1) s += __shfl_xor(s, o);
            const float mu = s * (1.f/128.f);
            const float d0 = v0 - mu, d1 = v1 - mu;
            float vs = d0*d0 + d1*d1;
            #pragma unroll
            for (int o = 32; o > 0; o >>= 1) vs += __shfl_xor(vs, o);
            const float rstd = rsqrtf(vs * (1.f/128.f) + 1e-5f);
            hA[r*128 + lane]      = d0*rstd*gl0 + bl0;
            hA[r*128 + lane + 64] = d1*rstd*gl1 + bl1;
        }
    }
    __syncthreads();

    // ---- projection 128 -> 512, fp32 write (+bf16-hi for k), head-major ----
    {
        const float* Wp = half ? Wk : Wq;
        const float* bp = half ? bk : bq;
        float* of = half ? kf : qf;
        const int j0 = tid, j1 = tid + 256;
        float acc0[16], acc1[16];
        #pragma unroll
        for (int r = 0; r < 16; ++r) { acc0[r] = 0.f; acc1[r] = 0.f; }
        float w0c[4], w1c[4];
        #pragma unroll
        for (int u = 0; u < 4; ++u) { w0c[u] = Wp[u*512 + j0]; w1c[u] = Wp[u*512 + j1]; }
        #pragma unroll 4
        for (int i = 0; i < 128; i += 4) {
            float w0n[4], w1n[4];
            const int ip = (i + 4 < 128) ? (i + 4) : i;
            #pragma unroll
            for (int u = 0; u < 4; ++u) { w0n[u] = Wp[(ip+u)*512 + j0]; w1n[u] = Wp[(ip+u)*512 + j1]; }
            #pragma unroll
            for (int r = 0; r < 16; ++r) {
                const float4 xv = *(const float4*)&hA[r*128 + i];
                acc0[r] = fmaf(xv.x, w0c[0], acc0[r]); acc1[r] = fmaf(xv.x, w1c[0], acc1[r]);
                acc0[r] = fmaf(xv.y, w0c[1], acc0[r]); acc1[r] = fmaf(xv.y, w1c[1], acc1[r]);
                acc0[r] = fmaf(xv.z, w0c[2], acc0[r]); acc1[r] = fmaf(xv.z, w1c[2], acc1[r]);
                acc0[r] = fmaf(xv.w, w0c[3], acc0[r]); acc1[r] = fmaf(xv.w, w1c[3], acc1[r]);
            }
            #pragma unroll
            for (int u = 0; u < 4; ++u) { w0c[u] = w0n[u]; w1c[u] = w1n[u]; }
        }
        const float bb0 = bp[j0], bb1 = bp[j1];
        const int h0 = j0 >> 7, d0 = j0 & 127;
        const int h1 = j1 >> 7, d1 = j1 & 127;
        #pragma unroll
        for (int r = 0; r < 16; ++r) {
            const int g  = row0 + r;
            const int bb = g >> 11, s = g & 2047;
            {
                const float v = acc0[r] + bb0;
                const size_t dst = ((size_t)(bb*4 + h0)*2048 + s)*128 + d0;
                of[dst] = v;
                if (half) khi[dst] = __float2bfloat16(v);
            }
            {
                const float v = acc1[r] + bb1;
                const size_t dst = ((size_t)(bb*4 + h1)*2048 + s)*128 + d1;
                of[dst] = v;
                if (half) khi[dst] = __float2bfloat16(v);
            }
        }
    }
}

// ---------------------------------------------------------------------------
// Kernel B: bf16-hi MFMA prefilter (operands swapped: A=K, B=Q so each lane
// owns one q-row's scores in-register) + branchless register top-20 + exact
// fp32 rescore + merge + quantiles. NO barriers / NO LDS in the K-loop.
// Lane (m16=lane&15, quad=lane>>4) of wave w owns q-row stile*64+w*16+m16;
// per 16-col sub-tile it gets k-cols colb+quad*4+reg (reg 0..3).
// Grid: flat 512, XCD-swizzled: bi&7 selects slab-pair -> slab L2-locality.
// Keys: (mono(score) & ~0x7FF) | col (21 score bits, 11 col bits).
// ---------------------------------------------------------------------------
__global__ __launch_bounds__(256) void k_scores_topk(
    const float* __restrict__ qf, const float* __restrict__ kf,
    const __hip_bfloat16* __restrict__ khi,
    const float* __restrict__ errors, const float* __restrict__ y,
    const float* __restrict__ y_pred,
    float* __restrict__ out, float* __restrict__ hacc)
{
    __shared__ float lv[20*256];           // 20480B exact scores [n][tid]
    __shared__ unsigned short lc[20*256];  // 10240B cols         [n][tid]
    __shared__ float ebuf[64*21];          // 5376B merge/sort buffer

    const int tid = threadIdx.x;
    const int bi  = blockIdx.x;
    // XCD swizzle: 32 blocks of one slab share bi%8 -> same XCD (heuristic)
    const int r8    = bi & 7;
    const int t     = bi >> 3;
    const int hb    = r8*2 + (t >> 5);   // slab index = b*4 + h
    const int stile = t & 31;
    const int b     = hb >> 2;
    const int h     = hb & 3;

    const int lane = tid & 63;
    const int w    = tid >> 6;
    const int m16  = lane & 15;
    const int quad = lane >> 4;

    const size_t slab = (size_t)hb * 2048;
    const __hip_bfloat16* slabp = khi + slab*128;

    // my q-row (owned by this lane end-to-end)
    const int sg_my = stile*64 + w*16 + m16;

    // Q fragment (B operand): B[n=m16][k=quad*8+j+ks*32] = q[w*16+n][k]
    short8v bq_[4];
    {
        const float* qp = qf + (slab + sg_my)*128 + quad*8;
        #pragma unroll
        for (int ks = 0; ks < 4; ++ks) {
            const float4 x0 = *(const float4*)(qp + ks*32);
            const float4 x1 = *(const float4*)(qp + ks*32 + 4);
            short8v tt;
            tt[0]=f2bf_s(x0.x); tt[1]=f2bf_s(x0.y); tt[2]=f2bf_s(x0.z); tt[3]=f2bf_s(x0.w);
            tt[4]=f2bf_s(x1.x); tt[5]=f2bf_s(x1.y); tt[6]=f2bf_s(x1.z); tt[7]=f2bf_s(x1.w);
            bq_[ks] = tt;
        }
    }

    // register-resident top-20 keys (ascending; keys[0] = current min)
    unsigned keys[20];
    #pragma unroll
    for (int n = 0; n < 20; ++n) keys[n] = 0u;

    #pragma unroll 2
    for (int mt = 0; mt < 32; ++mt) {
        #pragma unroll
        for (int ct = 0; ct < 4; ++ct) {
            const int colb = mt*64 + ct*16;
            // K fragment (A operand): A[m=m16][k=quad*8+j+ks*32] = khi[colb+m][k]
            const __hip_bfloat16* kp = slabp + (size_t)(colb + m16)*128 + quad*8;
            float4v acc = (float4v){0.f,0.f,0.f,0.f};
            #pragma unroll
            for (int ks = 0; ks < 4; ++ks) {
                const short8v ka = *(const short8v*)(kp + ks*32);
                acc = __builtin_amdgcn_mfma_f32_16x16x32_bf16(ka, bq_[ks], acc, 0, 0, 0);
            }
            const int cb = colb + quad*4;
            #pragma unroll
            for (int reg = 0; reg < 4; ++reg) {
                const int m = cb + reg;
                unsigned key = (mono(acc[reg]) & 0xFFFFF800u) | (unsigned)m;
                key = (m == sg_my) ? 0u : key;              // diagonal excluded
                keys[0] = (key > keys[0]) ? key : keys[0];  // drop-min insert
                #pragma unroll
                for (int i = 0; i < 19; ++i) {              // bubble restores order
                    const unsigned a = keys[i], c = keys[i+1];
                    keys[i]   = (a < c) ? a : c;
                    keys[i+1] = (a < c) ? c : a;
                }
            }
        }
    }

    // ---- exact fp32 rescore of this lane's 20 candidates (q-row sg_my) ----
    {
        const float* qrow_p = qf + (slab + (size_t)sg_my)*128;
        #pragma unroll 1
        for (int n = 0; n < 20; ++n) {
            const int col = (int)(keys[n] & 0x7FFu);
            const float* kcol = kf + (slab + (size_t)col)*128;
            float s0 = 0.f, s1 = 0.f, s2 = 0.f, s3 = 0.f;
            #pragma unroll 8
            for (int i = 0; i < 32; ++i) {
                const float4 qv = *(const float4*)(qrow_p + i*4);
                const float4 kv = *(const float4*)(kcol + i*4);
                s0 = fmaf(qv.x, kv.x, s0);
                s1 = fmaf(qv.y, kv.y, s1);
                s2 = fmaf(qv.z, kv.z, s2);
                s3 = fmaf(qv.w, kv.w, s3);
            }
            lv[n*256 + tid] = (s0 + s1) + (s2 + s3);
            lc[n*256 + tid] = (unsigned short)col;
        }
    }

    // ---- per-thread insertion sort (exact desc, col asc on ties) ----
    {
        for (int a = 1; a < 20; ++a) {
            const float v = lv[a*256 + tid];
            const unsigned short c = lc[a*256 + tid];
            int n = a;
            while (n > 0) {
                const float pv = lv[(n-1)*256 + tid];
                const unsigned short pc = lc[(n-1)*256 + tid];
                if (pv > v || (pv == v && pc < c)) break;
                lv[n*256 + tid] = pv;
                lc[n*256 + tid] = pc;
                --n;
            }
            lv[n*256 + tid] = v;
            lc[n*256 + tid] = c;
        }
    }
    __syncthreads();

    // ---- wave0 merges the 4 quad-lists of each row -> top-20 -> quantiles ----
    // row rr (0..63) = w*16+m16 -> lists at tid = (rr>>4)*64 + quad*16 + (rr&15)
    if (tid < 64) {
        const int rr = tid;
        const int lb = ((rr >> 4)*64) + (rr & 15);
        const int sg = stile*64 + rr;
        int p0 = 0, p1 = 0, p2 = 0, p3 = 0;
        float* e = &ebuf[rr*21];
        for (int n = 0; n < 20; ++n) {
            const float v0 = lv[p0*256 + lb     ];
            const float v1 = lv[p1*256 + lb + 16];
            const float v2 = lv[p2*256 + lb + 32];
            const float v3 = lv[p3*256 + lb + 48];
            const int c0 = lc[p0*256 + lb], c1 = lc[p1*256 + lb + 16];
            const int c2 = lc[p2*256 + lb + 32], c3 = lc[p3*256 + lb + 48];
            float bvv = v0; int bcc = c0; int bs = 0;
            if (v1 > bvv || (v1 == bvv && c1 < bcc)) { bvv=v1; bcc=c1; bs=1; }
            if (v2 > bvv || (v2 == bvv && c2 < bcc)) { bvv=v2; bcc=c2; bs=2; }
            if (v3 > bvv || (v3 == bvv && c3 < bcc)) { bvv=v3; bcc=c3; bs=3; }
            if (bs==0) ++p0; else if (bs==1) ++p1; else if (bs==2) ++p2; else ++p3;
            e[n] = errors[((size_t)(b*SS + bcc))*4];  // errors[..., 0]
        }
        for (int a = 1; a < 20; ++a) {     // insertion sort ascending
            const float v = e[a];
            int n = a;
            while (n > 0 && e[n-1] > v) { e[n] = e[n-1]; --n; }
            e[n] = v;
        }
        const float yp = y_pred[((size_t)(b*SS + sg))*4];
        const float yt = y[((size_t)(b*SS + sg))*4];
        float msum = 0.f;
        const size_t obase = ((size_t)(h*4 + b)*18)*2048 + sg;
        #pragma unroll 1
        for (int a = 0; a < 18; ++a) {
            const float alpha = c_alphas[a];
            const float beta  = 0.5f*alpha;
            const float pl = beta * 19.f;
            const int   il = (int)pl;
            const float fl = pl - (float)il;
            const float ql = e[il]*(1.f-fl) + e[il+1]*fl;
            const float qq = (1.f - alpha) + beta;
            const float ph = qq * 19.f;
            const int   ih = (int)ph;
            const float fh = ph - (float)ih;
            const float qh = e[ih]*(1.f-fh) + e[ih+1]*fh;
            msum += ql + qh;
            const size_t oidx = obase + (size_t)a*2048;
            out[OFF_YLOW  + oidx] = ql + yp;
            out[OFF_YHIGH + oidx] = qh + yp;
            out[OFF_QLOW  + oidx] = ql;
            out[OFF_QHIGH + oidx] = qh;
        }
        const float me = msum * (1.f/36.f);
        const float dd = yt - (me + yp);
        float sq = dd*dd;
        #pragma unroll
        for (int o = 32; o > 0; o >>= 1) sq += __shfl_xor(sq, o);
        if (rr == 0) atomicAdd(&hacc[h], sq);
    }
}

__global__ void k_init(float* __restrict__ hacc) {
    if (threadIdx.x < 4) hacc[threadIdx.x] = 0.f;
}

__global__ __launch_bounds__(256) void k_finalize(
    const float* __restrict__ y, const float* __restrict__ y_pred,
    const float* __restrict__ errors, const float* __restrict__ hacc,
    float* __restrict__ out)
{
    const int i = blockIdx.x*256 + threadIdx.x;
    if (i == 0)
        out[0] = (hacc[0]+hacc[1]+hacc[2]+hacc[3]) * (1.f/32768.f);
    if (i < 32768)      out[OFF_Y + i] = y[i];
    else if (i < 65536) out[OFF_YPRED + (i - 32768)] = y_pred[i - 32768];
    else if (i < 73728) { const int j = i - 65536; out[OFF_ERR + j] = errors[(size_t)j*4]; }
}

extern "C" void kernel_launch(void* const* d_in, const int* in_sizes, int n_in,
                              void* d_out, int out_size, void* d_ws, size_t ws_size,
                              hipStream_t stream)
{
    const float* Xt     = (const float*)d_in[0];
    const float* Xs     = (const float*)d_in[1];
    const float* errors = (const float*)d_in[2];
    const float* y      = (const float*)d_in[3];
    const float* y_pred = (const float*)d_in[4];
    const float* W1 = (const float*)d_in[5];   const float* b1 = (const float*)d_in[6];
    const float* W2 = (const float*)d_in[7];   const float* b2 = (const float*)d_in[8];
    const float* W3 = (const float*)d_in[9];   const float* b3 = (const float*)d_in[10];
    const float* W4 = (const float*)d_in[11];  const float* b4 = (const float*)d_in[12];
    const float* Wq = (const float*)d_in[13];  const float* bq = (const float*)d_in[14];
    const float* Wk = (const float*)d_in[15];  const float* bk = (const float*)d_in[16];
    const float* g_q    = (const float*)d_in[17];
    const float* beta_q = (const float*)d_in[18];
    const float* g_k    = (const float*)d_in[19];
    const float* beta_k = (const float*)d_in[20];

    float* out  = (float*)d_out;
    float* hacc = (float*)d_ws;
    const size_t SLAB = (size_t)16*2048*128;   // 4,194,304 elements
    float* qf = (float*)d_ws + 16;             // 16MB
    float* kf = qf + SLAB;                     // 16MB
    __hip_bfloat16* khi = (__hip_bfloat16*)(kf + SLAB);  // 8MB

    k_init<<<1, 64, 0, stream>>>(hacc);
    k_mlp<<<1024, 256, 0, stream>>>(Xt, Xs, W1,b1,W2,b2,W3,b3,W4,b4,
                                    Wq,bq,Wk,bk,g_q,beta_q,g_k,beta_k,
                                    qf, kf, khi);
    k_scores_topk<<<512, 256, 0, stream>>>(qf, kf, khi,
                                           errors, y, y_pred, out, hacc);
    k_finalize<<<288, 256, 0, stream>>>(y, y_pred, errors, hacc, out);
}

// Round 6
// 846.215 us; speedup vs baseline: 1.2065x; 1.2065x over previous
//
#include <hip/hip_runtime.h>
#include <hip/hip_bf16.h>
#include <math.h>

// ConformHopfieldBatch: B=4 S=2048 IN=64 D=128 HID=400 H=4 K=20 NQ=18
// softmax monotone -> top_k(assoc) == top_k(raw scores). bf16-hi MFMA
// PREFILTER (A=K,B=Q operand swap: lane owns its q-row's scores in-register,
// zero barriers/LDS in K-loop) -> 80 candidates/row; exact fp32 RESCORE
// selects true top-20 (R2 lesson: selection needs fp32-exact scores).
// R5 postmortem: (a) k_mlp manual weight-prefetch defeated compiler
// scheduling (340->522us) -> reverted to R4 bodies, kept xa-alias only;
// (b) rescore was TA-bound: per-lane scattered gathers = 64 cache lines per
// load instr (~270us). R6: COOPERATIVE rescore -- 4 lanes of a row split each
// candidate's 128-float k-col into 4x32 interleaved segments (16x64B
// contiguous segments per instr), q segment register-resident, cross-quad
// butterfly reduce (2 shfl_xor). R1 lesson: lane-transposed LDS lists.

#define SS 2048

typedef short short8v __attribute__((ext_vector_type(8)));
typedef float float4v __attribute__((ext_vector_type(4)));

__constant__ float c_alphas[18] = {0.05f,0.06f,0.08f,0.1f,0.12f,0.14f,0.15f,0.17f,
                                   0.19f,0.2f,0.21f,0.23f,0.25f,0.3f,0.35f,0.38f,0.4f,0.45f};

// output flat offsets (return-order concat)
#define OFF_Y      1
#define OFF_YPRED  32769
#define OFF_YLOW   65537ll
#define OFF_YHIGH  655361ll
#define OFF_ERR    1245185ll
#define OFF_QLOW   1253377ll
#define OFF_QHIGH  1843201ll

__device__ inline short f2bf_s(float f) {
    __hip_bfloat16 h = __float2bfloat16(f);
    return __builtin_bit_cast(short, h);
}
// monotone fp32 -> u32 map (order-preserving)
__device__ inline unsigned mono(float f) {
    unsigned u = __builtin_bit_cast(unsigned, f);
    return (u & 0x80000000u) ? ~u : (u | 0x80000000u);
}

// ---------------------------------------------------------------------------
// Kernel A: fused MLP(64->400->400->400->128) + LayerNorm + projection(128->512)
// 16 rows/block, 256 threads. blocks 0..511: true->q (fp32); 512..1023: sim->k
// (fp32 + bf16-hi). Head-major layout [(b*4+h)][s][128].
// R4 loop bodies (compiler-scheduled); xa aliases hB (LDS 51.2KB, 3 blocks/CU).
// ---------------------------------------------------------------------------
__global__ __launch_bounds__(256) void k_mlp(
    const float* __restrict__ Xt, const float* __restrict__ Xs,
    const float* __restrict__ W1, const float* __restrict__ b1,
    const float* __restrict__ W2, const float* __restrict__ b2,
    const float* __restrict__ W3, const float* __restrict__ b3,
    const float* __restrict__ W4, const float* __restrict__ b4,
    const float* __restrict__ Wq, const float* __restrict__ bq,
    const float* __restrict__ Wk, const float* __restrict__ bk,
    const float* __restrict__ g_q, const float* __restrict__ beta_q,
    const float* __restrict__ g_k, const float* __restrict__ beta_k,
    float* __restrict__ qf, float* __restrict__ kf,
    __hip_bfloat16* __restrict__ khi)
{
    __shared__ float hA[16*400];   // 25.6KB
    __shared__ float hB[16*400];   // 25.6KB; first 1024 floats double as xa
    float* xa = hB;

    const int tid  = threadIdx.x;
    const int half = (blockIdx.x >= 512) ? 1 : 0;
    const int row0 = (blockIdx.x & 511) * 16;
    const float* X = half ? Xs : Xt;

    {
        const float4* src = (const float4*)(X + (size_t)row0 * 64);
        ((float4*)xa)[tid] = src[tid];
    }
    __syncthreads();

    // ---- layer 1: 64 -> 400 (relu), xa(=hB) -> hA ----
    {
        const int j0 = tid, j1 = tid + 256;
        const bool v1 = (j1 < 400);
        const int j1m = v1 ? j1 : j0;
        float acc0[16], acc1[16];
        #pragma unroll
        for (int r = 0; r < 16; ++r) { acc0[r] = 0.f; acc1[r] = 0.f; }
        #pragma unroll 2
        for (int i = 0; i < 64; i += 4) {
            float w0a[4], w1a[4];
            #pragma unroll
            for (int u = 0; u < 4; ++u) { w0a[u] = W1[(i+u)*400 + j0]; w1a[u] = W1[(i+u)*400 + j1m]; }
            #pragma unroll
            for (int r = 0; r < 16; ++r) {
                const float4 xv = *(const float4*)&xa[r*64 + i];
                acc0[r] = fmaf(xv.x, w0a[0], acc0[r]); acc1[r] = fmaf(xv.x, w1a[0], acc1[r]);
                acc0[r] = fmaf(xv.y, w0a[1], acc0[r]); acc1[r] = fmaf(xv.y, w1a[1], acc1[r]);
                acc0[r] = fmaf(xv.z, w0a[2], acc0[r]); acc1[r] = fmaf(xv.z, w1a[2], acc1[r]);
                acc0[r] = fmaf(xv.w, w0a[3], acc0[r]); acc1[r] = fmaf(xv.w, w1a[3], acc1[r]);
            }
        }
        const float bb0 = b1[j0], bb1 = b1[j1m];
        #pragma unroll
        for (int r = 0; r < 16; ++r) {
            hA[r*400 + j0] = fmaxf(acc0[r] + bb0, 0.f);
            if (v1) hA[r*400 + j1] = fmaxf(acc1[r] + bb1, 0.f);
        }
    }
    __syncthreads();

    // ---- layer 2: 400 -> 400 (relu), hA -> hB ----
    {
        const int j0 = tid, j1 = tid + 256;
        const bool v1 = (j1 < 400);
        const int j1m = v1 ? j1 : j0;
        float acc0[16], acc1[16];
        #pragma unroll
        for (int r = 0; r < 16; ++r) { acc0[r] = 0.f; acc1[r] = 0.f; }
        #pragma unroll 2
        for (int i = 0; i < 400; i += 4) {
            float w0a[4], w1a[4];
            #pragma unroll
            for (int u = 0; u < 4; ++u) { w0a[u] = W2[(i+u)*400 + j0]; w1a[u] = W2[(i+u)*400 + j1m]; }
            #pragma unroll
            for (int r = 0; r < 16; ++r) {
                const float4 xv = *(const float4*)&hA[r*400 + i];
                acc0[r] = fmaf(xv.x, w0a[0], acc0[r]); acc1[r] = fmaf(xv.x, w1a[0], acc1[r]);
                acc0[r] = fmaf(xv.y, w0a[1], acc0[r]); acc1[r] = fmaf(xv.y, w1a[1], acc1[r]);
                acc0[r] = fmaf(xv.z, w0a[2], acc0[r]); acc1[r] = fmaf(xv.z, w1a[2], acc1[r]);
                acc0[r] = fmaf(xv.w, w0a[3], acc0[r]); acc1[r] = fmaf(xv.w, w1a[3], acc1[r]);
            }
        }
        const float bb0 = b2[j0], bb1 = b2[j1m];
        #pragma unroll
        for (int r = 0; r < 16; ++r) {
            hB[r*400 + j0] = fmaxf(acc0[r] + bb0, 0.f);
            if (v1) hB[r*400 + j1] = fmaxf(acc1[r] + bb1, 0.f);
        }
    }
    __syncthreads();

    // ---- layer 3: 400 -> 400 (relu), hB -> hA ----
    {
        const int j0 = tid, j1 = tid + 256;
        const bool v1 = (j1 < 400);
        const int j1m = v1 ? j1 : j0;
        float acc0[16], acc1[16];
        #pragma unroll
        for (int r = 0; r < 16; ++r) { acc0[r] = 0.f; acc1[r] = 0.f; }
        #pragma unroll 2
        for (int i = 0; i < 400; i += 4) {
            float w0a[4], w1a[4];
            #pragma unroll
            for (int u = 0; u < 4; ++u) { w0a[u] = W3[(i+u)*400 + j0]; w1a[u] = W3[(i+u)*400 + j1m]; }
            #pragma unroll
            for (int r = 0; r < 16; ++r) {
                const float4 xv = *(const float4*)&hB[r*400 + i];
                acc0[r] = fmaf(xv.x, w0a[0], acc0[r]); acc1[r] = fmaf(xv.x, w1a[0], acc1[r]);
                acc0[r] = fmaf(xv.y, w0a[1], acc0[r]); acc1[r] = fmaf(xv.y, w1a[1], acc1[r]);
                acc0[r] = fmaf(xv.z, w0a[2], acc0[r]); acc1[r] = fmaf(xv.z, w1a[2], acc1[r]);
                acc0[r] = fmaf(xv.w, w0a[3], acc0[r]); acc1[r] = fmaf(xv.w, w1a[3], acc1[r]);
            }
        }
        const float bb0 = b3[j0], bb1 = b3[j1m];
        #pragma unroll
        for (int r = 0; r < 16; ++r) {
            hA[r*400 + j0] = fmaxf(acc0[r] + bb0, 0.f);
            if (v1) hA[r*400 + j1] = fmaxf(acc1[r] + bb1, 0.f);
        }
    }
    __syncthreads();

    // ---- layer 4: 400 -> 128 (no relu), hA -> hB (stride 128) ----
    {
        const int j  = tid & 127;
        const int r0 = (tid >> 7) * 8;
        float acc[8];
        #pragma unroll
        for (int r = 0; r < 8; ++r) acc[r] = 0.f;
        #pragma unroll 2
        for (int i = 0; i < 400; i += 4) {
            float wa[4];
            #pragma unroll
            for (int u = 0; u < 4; ++u) wa[u] = W4[(i+u)*128 + j];
            #pragma unroll
            for (int r = 0; r < 8; ++r) {
                const float4 xv = *(const float4*)&hA[(r0+r)*400 + i];
                acc[r] = fmaf(xv.x, wa[0], acc[r]);
                acc[r] = fmaf(xv.y, wa[1], acc[r]);
                acc[r] = fmaf(xv.z, wa[2], acc[r]);
                acc[r] = fmaf(xv.w, wa[3], acc[r]);
            }
        }
        const float bb = b4[j];
        #pragma unroll
        for (int r = 0; r < 8; ++r)
            hB[(r0+r)*128 + j] = acc[r] + bb;
    }
    __syncthreads();

    // ---- LayerNorm -> hA (stride 128) ----
    {
        const float* g  = half ? g_k : g_q;
        const float* be = half ? beta_k : beta_q;
        const int lane = tid & 63;
        const int wg   = tid >> 6;
        const float gl0 = g[lane],  gl1 = g[lane+64];
        const float bl0 = be[lane], bl1 = be[lane+64];
        #pragma unroll 1
        for (int d = 0; d < 4; ++d) {
            const int r = wg*4 + d;
            const float v0 = hB[r*128 + lane];
            const float v1 = hB[r*128 + lane + 64];
            float s = v0 + v1;
            #pragma unroll
            for (int o = 32; o > 0; o >>= 1) s += __shfl_xor(s, o);
            const float mu = s * (1.f/128.f);
            const float d0 = v0 - mu, d1 = v1 - mu;
            float vs = d0*d0 + d1*d1;
            #pragma unroll
            for (int o = 32; o > 0; o >>= 1) vs += __shfl_xor(vs, o);
            const float rstd = rsqrtf(vs * (1.f/128.f) + 1e-5f);
            hA[r*128 + lane]      = d0*rstd*gl0 + bl0;
            hA[r*128 + lane + 64] = d1*rstd*gl1 + bl1;
        }
    }
    __syncthreads();

    // ---- projection 128 -> 512, fp32 write (+bf16-hi for k), head-major ----
    {
        const float* Wp = half ? Wk : Wq;
        const float* bp = half ? bk : bq;
        float* of = half ? kf : qf;
        const int j0 = tid, j1 = tid + 256;
        float acc0[16], acc1[16];
        #pragma unroll
        for (int r = 0; r < 16; ++r) { acc0[r] = 0.f; acc1[r] = 0.f; }
        #pragma unroll 2
        for (int i = 0; i < 128; i += 4) {
            float w0a[4], w1a[4];
            #pragma unroll
            for (int u = 0; u < 4; ++u) { w0a[u] = Wp[(i+u)*512 + j0]; w1a[u] = Wp[(i+u)*512 + j1]; }
            #pragma unroll
            for (int r = 0; r < 16; ++r) {
                const float4 xv = *(const float4*)&hA[r*128 + i];
                acc0[r] = fmaf(xv.x, w0a[0], acc0[r]); acc1[r] = fmaf(xv.x, w1a[0], acc1[r]);
                acc0[r] = fmaf(xv.y, w0a[1], acc0[r]); acc1[r] = fmaf(xv.y, w1a[1], acc1[r]);
                acc0[r] = fmaf(xv.z, w0a[2], acc0[r]); acc1[r] = fmaf(xv.z, w1a[2], acc1[r]);
                acc0[r] = fmaf(xv.w, w0a[3], acc0[r]); acc1[r] = fmaf(xv.w, w1a[3], acc1[r]);
            }
        }
        const float bb0 = bp[j0], bb1 = bp[j1];
        const int h0 = j0 >> 7, d0 = j0 & 127;
        const int h1 = j1 >> 7, d1 = j1 & 127;
        #pragma unroll
        for (int r = 0; r < 16; ++r) {
            const int g  = row0 + r;
            const int bb = g >> 11, s = g & 2047;
            {
                const float v = acc0[r] + bb0;
                const size_t dst = ((size_t)(bb*4 + h0)*2048 + s)*128 + d0;
                of[dst] = v;
                if (half) khi[dst] = __float2bfloat16(v);
            }
            {
                const float v = acc1[r] + bb1;
                const size_t dst = ((size_t)(bb*4 + h1)*2048 + s)*128 + d1;
                of[dst] = v;
                if (half) khi[dst] = __float2bfloat16(v);
            }
        }
    }
}

// ---------------------------------------------------------------------------
// Kernel B: bf16-hi MFMA prefilter (A=K, B=Q swap; lane owns q-row's scores
// in-register; zero barriers in K-loop) + branchless register top-20 +
// COOPERATIVE exact fp32 rescore (4 lanes/row, coalesced 64B segments,
// butterfly reduce) + merge + quantiles.
// Grid: flat 512, XCD-swizzled (32 blocks of one slab -> same XCD).
// Keys: (mono(score) & ~0x7FF) | col (21 score bits, 11 col bits).
// ---------------------------------------------------------------------------
__global__ __launch_bounds__(256) void k_scores_topk(
    const float* __restrict__ qf, const float* __restrict__ kf,
    const __hip_bfloat16* __restrict__ khi,
    const float* __restrict__ errors, const float* __restrict__ y,
    const float* __restrict__ y_pred,
    float* __restrict__ out, float* __restrict__ hacc)
{
    __shared__ float lv[20*256];           // 20480B exact scores [n][tid]
    __shared__ unsigned short lc[20*256];  // 10240B cols         [n][tid]
    __shared__ float ebuf[64*21];          // 5376B merge/sort buffer

    const int tid = threadIdx.x;
    const int bi  = blockIdx.x;
    // XCD swizzle: 32 blocks of one slab share bi%8 -> same XCD (heuristic)
    const int r8    = bi & 7;
    const int t     = bi >> 3;
    const int hb    = r8*2 + (t >> 5);   // slab index = b*4 + h
    const int stile = t & 31;
    const int b     = hb >> 2;
    const int h     = hb & 3;

    const int lane = tid & 63;
    const int w    = tid >> 6;
    const int m16  = lane & 15;
    const int quad = lane >> 4;

    const size_t slab = (size_t)hb * 2048;
    const __hip_bfloat16* slabp = khi + slab*128;

    // my q-row (owned end-to-end by this lane's quad group)
    const int sg_my = stile*64 + w*16 + m16;
    const float* qrow_p = qf + (slab + (size_t)sg_my)*128;

    // Q fragment (B operand): B[n=m16][k=quad*8+j+ks*32] = q[w*16+n][k]
    short8v bq_[4];
    {
        const float* qp = qrow_p + quad*8;
        #pragma unroll
        for (int ks = 0; ks < 4; ++ks) {
            const float4 x0 = *(const float4*)(qp + ks*32);
            const float4 x1 = *(const float4*)(qp + ks*32 + 4);
            short8v tt;
            tt[0]=f2bf_s(x0.x); tt[1]=f2bf_s(x0.y); tt[2]=f2bf_s(x0.z); tt[3]=f2bf_s(x0.w);
            tt[4]=f2bf_s(x1.x); tt[5]=f2bf_s(x1.y); tt[6]=f2bf_s(x1.z); tt[7]=f2bf_s(x1.w);
            bq_[ks] = tt;
        }
    }

    // fp32 q segment for cooperative rescore: floats [quad*4 + u*16, +4)
    float4 qseg[8];
    #pragma unroll
    for (int u = 0; u < 8; ++u)
        qseg[u] = *(const float4*)(qrow_p + quad*4 + u*16);

    // register-resident top-20 keys (ascending; keys[0] = current min)
    unsigned keys[20];
    #pragma unroll
    for (int n = 0; n < 20; ++n) keys[n] = 0u;

    #pragma unroll 2
    for (int mt = 0; mt < 32; ++mt) {
        #pragma unroll
        for (int ct = 0; ct < 4; ++ct) {
            const int colb = mt*64 + ct*16;
            // K fragment (A operand): A[m=m16][k=quad*8+j+ks*32] = khi[colb+m][k]
            const __hip_bfloat16* kp = slabp + (size_t)(colb + m16)*128 + quad*8;
            float4v acc = (float4v){0.f,0.f,0.f,0.f};
            #pragma unroll
            for (int ks = 0; ks < 4; ++ks) {
                const short8v ka = *(const short8v*)(kp + ks*32);
                acc = __builtin_amdgcn_mfma_f32_16x16x32_bf16(ka, bq_[ks], acc, 0, 0, 0);
            }
            const int cb = colb + quad*4;
            #pragma unroll
            for (int reg = 0; reg < 4; ++reg) {
                const int m = cb + reg;
                unsigned key = (mono(acc[reg]) & 0xFFFFF800u) | (unsigned)m;
                key = (m == sg_my) ? 0u : key;              // diagonal excluded
                keys[0] = (key > keys[0]) ? key : keys[0];  // drop-min insert
                #pragma unroll
                for (int i = 0; i < 19; ++i) {              // bubble restores order
                    const unsigned a = keys[i], c = keys[i+1];
                    keys[i]   = (a < c) ? a : c;
                    keys[i+1] = (a < c) ? c : a;
                }
            }
        }
    }

    // ---- cooperative exact fp32 rescore: 4 lanes per row per candidate ----
    // Owner quad p broadcasts col; lane (quad j) computes partial over its
    // 32-float interleaved segment; butterfly-sum over quads; owner stores.
    const float* kslab = kf + slab*128;
    #pragma unroll 1
    for (int p = 0; p < 4; ++p) {
        #pragma unroll
        for (int n = 0; n < 20; ++n) {
            const int col = __shfl((int)(keys[n] & 0x7FFu), p*16 + m16);
            const float* kc = kslab + (size_t)col*128 + quad*4;
            float4v s = (float4v){0.f,0.f,0.f,0.f};
            #pragma unroll
            for (int u = 0; u < 8; ++u) {
                const float4 kv = *(const float4*)(kc + u*16);
                s[0] = fmaf(qseg[u].x, kv.x, s[0]);
                s[1] = fmaf(qseg[u].y, kv.y, s[1]);
                s[2] = fmaf(qseg[u].z, kv.z, s[2]);
                s[3] = fmaf(qseg[u].w, kv.w, s[3]);
            }
            float v = (s[0] + s[1]) + (s[2] + s[3]);
            v += __shfl_xor(v, 16);
            v += __shfl_xor(v, 32);
            if (p == quad) {
                lv[n*256 + tid] = v;
                lc[n*256 + tid] = (unsigned short)col;
            }
        }
    }

    // ---- per-thread insertion sort (exact desc, col asc on ties) ----
    {
        for (int a = 1; a < 20; ++a) {
            const float v = lv[a*256 + tid];
            const unsigned short c = lc[a*256 + tid];
            int n = a;
            while (n > 0) {
                const float pv = lv[(n-1)*256 + tid];
                const unsigned short pc = lc[(n-1)*256 + tid];
                if (pv > v || (pv == v && pc < c)) break;
                lv[n*256 + tid] = pv;
                lc[n*256 + tid] = pc;
                --n;
            }
            lv[n*256 + tid] = v;
            lc[n*256 + tid] = c;
        }
    }
    __syncthreads();

    // ---- wave0 merges the 4 quad-lists of each row -> top-20 -> quantiles ----
    // row rr (0..63) = w*16+m16 -> lists at tid = (rr>>4)*64 + quad*16 + (rr&15)
    if (tid < 64) {
        const int rr = tid;
        const int lb = ((rr >> 4)*64) + (rr & 15);
        const int sg = stile*64 + rr;
        int p0 = 0, p1 = 0, p2 = 0, p3 = 0;
        float* e = &ebuf[rr*21];
        for (int n = 0; n < 20; ++n) {
            const float v0 = lv[p0*256 + lb     ];
            const float v1 = lv[p1*256 + lb + 16];
            const float v2 = lv[p2*256 + lb + 32];
            const float v3 = lv[p3*256 + lb + 48];
            const int c0 = lc[p0*256 + lb], c1 = lc[p1*256 + lb + 16];
            const int c2 = lc[p2*256 + lb + 32], c3 = lc[p3*256 + lb + 48];
            float bvv = v0; int bcc = c0; int bs = 0;
            if (v1 > bvv || (v1 == bvv && c1 < bcc)) { bvv=v1; bcc=c1; bs=1; }
            if (v2 > bvv || (v2 == bvv && c2 < bcc)) { bvv=v2; bcc=c2; bs=2; }
            if (v3 > bvv || (v3 == bvv && c3 < bcc)) { bvv=v3; bcc=c3; bs=3; }
            if (bs==0) ++p0; else if (bs==1) ++p1; else if (bs==2) ++p2; else ++p3;
            e[n] = errors[((size_t)(b*SS + bcc))*4];  // errors[..., 0]
        }
        for (int a = 1; a < 20; ++a) {     // insertion sort ascending
            const float v = e[a];
            int n = a;
            while (n > 0 && e[n-1] > v) { e[n] = e[n-1]; --n; }
            e[n] = v;
        }
        const float yp = y_pred[((size_t)(b*SS + sg))*4];
        const float yt = y[((size_t)(b*SS + sg))*4];
        float msum = 0.f;
        const size_t obase = ((size_t)(h*4 + b)*18)*2048 + sg;
        #pragma unroll 1
        for (int a = 0; a < 18; ++a) {
            const float alpha = c_alphas[a];
            const float beta  = 0.5f*alpha;
            const float pl = beta * 19.f;
            const int   il = (int)pl;
            const float fl = pl - (float)il;
            const float ql = e[il]*(1.f-fl) + e[il+1]*fl;
            const float qq = (1.f - alpha) + beta;
            const float ph = qq * 19.f;
            const int   ih = (int)ph;
            const float fh = ph - (float)ih;
            const float qh = e[ih]*(1.f-fh) + e[ih+1]*fh;
            msum += ql + qh;
            const size_t oidx = obase + (size_t)a*2048;
            out[OFF_YLOW  + oidx] = ql + yp;
            out[OFF_YHIGH + oidx] = qh + yp;
            out[OFF_QLOW  + oidx] = ql;
            out[OFF_QHIGH + oidx] = qh;
        }
        const float me = msum * (1.f/36.f);
        const float dd = yt - (me + yp);
        float sq = dd*dd;
        #pragma unroll
        for (int o = 32; o > 0; o >>= 1) sq += __shfl_xor(sq, o);
        if (rr == 0) atomicAdd(&hacc[h], sq);
    }
}

__global__ void k_init(float* __restrict__ hacc) {
    if (threadIdx.x < 4) hacc[threadIdx.x] = 0.f;
}

__global__ __launch_bounds__(256) void k_finalize(
    const float* __restrict__ y, const float* __restrict__ y_pred,
    const float* __restrict__ errors, const float* __restrict__ hacc,
    float* __restrict__ out)
{
    const int i = blockIdx.x*256 + threadIdx.x;
    if (i == 0)
        out[0] = (hacc[0]+hacc[1]+hacc[2]+hacc[3]) * (1.f/32768.f);
    if (i < 32768)      out[OFF_Y + i] = y[i];
    else if (i < 65536) out[OFF_YPRED + (i - 32768)] = y_pred[i - 32768];
    else if (i < 73728) { const int j = i - 65536; out[OFF_ERR + j] = errors[(size_t)j*4]; }
}

extern "C" void kernel_launch(void* const* d_in, const int* in_sizes, int n_in,
                              void* d_out, int out_size, void* d_ws, size_t ws_size,
                              hipStream_t stream)
{
    const float* Xt     = (const float*)d_in[0];
    const float* Xs     = (const float*)d_in[1];
    const float* errors = (const float*)d_in[2];
    const float* y      = (const float*)d_in[3];
    const float* y_pred = (const float*)d_in[4];
    const float* W1 = (const float*)d_in[5];   const float* b1 = (const float*)d_in[6];
    const float* W2 = (const float*)d_in[7];   const float* b2 = (const float*)d_in[8];
    const float* W3 = (const float*)d_in[9];   const float* b3 = (const float*)d_in[10];
    const float* W4 = (const float*)d_in[11];  const float* b4 = (const float*)d_in[12];
    const float* Wq = (const float*)d_in[13];  const float* bq = (const float*)d_in[14];
    const float* Wk = (const float*)d_in[15];  const float* bk = (const float*)d_in[16];
    const float* g_q    = (const float*)d_in[17];
    const float* beta_q = (const float*)d_in[18];
    const float* g_k    = (const float*)d_in[19];
    const float* beta_k = (const float*)d_in[20];

    float* out  = (float*)d_out;
    float* hacc = (float*)d_ws;
    const size_t SLAB = (size_t)16*2048*128;   // 4,194,304 elements
    float* qf = (float*)d_ws + 16;             // 16MB
    float* kf = qf + SLAB;                     // 16MB
    __hip_bfloat16* khi = (__hip_bfloat16*)(kf + SLAB);  // 8MB

    k_init<<<1, 64, 0, stream>>>(hacc);
    k_mlp<<<1024, 256, 0, stream>>>(Xt, Xs, W1,b1,W2,b2,W3,b3,W4,b4,
                                    Wq,bq,Wk,bk,g_q,beta_q,g_k,beta_k,
                                    qf, kf, khi);
    k_scores_topk<<<512, 256, 0, stream>>>(qf, kf, khi,
                                           errors, y, y_pred, out, hacc);
    k_finalize<<<288, 256, 0, stream>>>(y, y_pred, errors, hacc, out);
}

// Round 7
// 733.154 us; speedup vs baseline: 1.3926x; 1.1542x over previous
//
#include <hip/hip_runtime.h>
#include <hip/hip_bf16.h>
#include <math.h>

// ConformHopfieldBatch: B=4 S=2048 IN=64 D=128 HID=400 H=4 K=20 NQ=18
// softmax monotone -> top_k(assoc) == top_k(raw scores). bf16-hi MFMA
// PREFILTER (A=K,B=Q swap; lane owns its q-row's scores in-register, zero
// barriers in the scan) -> approx candidates; exact fp32 RESCORE selects the
// true top-20 (R2 lesson: selection needs fp32-exact scores).
// R6 postmortem: k_mlp was LDS-PIPE-bound (84% busy on redundant per-wave
// broadcast ds_read_b128) -> R7 k_mlp holds activations in REGISTERS and
// broadcasts via v_readlane: 64-thread blocks, 8 rows, 7 cols/lane, ZERO LDS.
// FMA i-order unchanged -> enc bit-identical (LN reduce reordered ~1e-7, safe
// per R1/R3). k_scores was occupancy-capped (grid 512) -> split:
//   k_scan (grid 2048, m-quarters): scan + per-block approx-top-24/row keys
//   k_select: merge 4x24 -> approx-top-32 -> coop exact rescore -> top-20
// Safety: per-quad depth-20 (stream can hold <=19 true-above + eps-flips),
// block depth-24, final cut 32 -- order-stat margins ~1.0 >> 2*eps=0.034.

#define SS 2048

typedef short short8v __attribute__((ext_vector_type(8)));
typedef float float4v __attribute__((ext_vector_type(4)));

__constant__ float c_alphas[18] = {0.05f,0.06f,0.08f,0.1f,0.12f,0.14f,0.15f,0.17f,
                                   0.19f,0.2f,0.21f,0.23f,0.25f,0.3f,0.35f,0.38f,0.4f,0.45f};

// output flat offsets (return-order concat)
#define OFF_Y      1
#define OFF_YPRED  32769
#define OFF_YLOW   65537ll
#define OFF_YHIGH  655361ll
#define OFF_ERR    1245185ll
#define OFF_QLOW   1253377ll
#define OFF_QHIGH  1843201ll

__device__ inline short f2bf_s(float f) {
    __hip_bfloat16 h = __float2bfloat16(f);
    return __builtin_bit_cast(short, h);
}
// monotone fp32 -> u32 map (order-preserving)
__device__ inline unsigned mono(float f) {
    unsigned u = __builtin_bit_cast(unsigned, f);
    return (u & 0x80000000u) ? ~u : (u | 0x80000000u);
}
// wave-uniform register broadcast (v_readlane_b32)
__device__ inline float rdlane(float v, int l) {
    return __builtin_bit_cast(float, __builtin_amdgcn_readlane(__builtin_bit_cast(int, v), l));
}

// ---------------------------------------------------------------------------
// Kernel A: fused MLP + LayerNorm + projection. 64 threads, 8 rows/block.
// Activations register-resident: lane t holds cols {c*64+t} of every row;
// broadcast via readlane. No LDS. blocks 0..1023: true->q; 1024..2047: sim->k.
// Head-major fp32 out [(b*4+h)][s][128]; bf16-hi of k for the MFMA scan.
// ---------------------------------------------------------------------------
__global__ __launch_bounds__(64) void k_mlp(
    const float* __restrict__ Xt, const float* __restrict__ Xs,
    const float* __restrict__ W1, const float* __restrict__ b1,
    const float* __restrict__ W2, const float* __restrict__ b2,
    const float* __restrict__ W3, const float* __restrict__ b3,
    const float* __restrict__ W4, const float* __restrict__ b4,
    const float* __restrict__ Wq, const float* __restrict__ bq,
    const float* __restrict__ Wk, const float* __restrict__ bk,
    const float* __restrict__ g_q, const float* __restrict__ beta_q,
    const float* __restrict__ g_k, const float* __restrict__ beta_k,
    float* __restrict__ qf, float* __restrict__ kf,
    __hip_bfloat16* __restrict__ khi)
{
    const int t    = threadIdx.x;          // 0..63
    const int bi   = blockIdx.x;
    const int half = bi >> 10;             // 0:true/q 1:sim/k
    const int rbase = (bi & 1023) * 8;     // row group within half
    const float* X = half ? Xs : Xt;

    int jm[7];                             // clamped col ids for 400-wide layers
    #pragma unroll
    for (int cc = 0; cc < 7; ++cc) { int j = cc*64 + t; jm[cc] = (j < 400) ? j : 399; }

    // input rows into registers: lane t holds x[r][t]
    float xreg[8];
    #pragma unroll
    for (int r = 0; r < 8; ++r) xreg[r] = X[(size_t)(rbase + r)*64 + t];

    float A1[8][7], A2[8][7];

    // ---- layer 1: 64 -> 400 (relu), xreg -> A1 ----
    {
        #pragma unroll
        for (int r = 0; r < 8; ++r)
            #pragma unroll
            for (int cc = 0; cc < 7; ++cc) A1[r][cc] = 0.f;
        #pragma unroll 4
        for (int il = 0; il < 64; ++il) {
            float wv[7];
            #pragma unroll
            for (int cc = 0; cc < 7; ++cc) wv[cc] = W1[il*400 + jm[cc]];
            #pragma unroll
            for (int r = 0; r < 8; ++r) {
                const float x = rdlane(xreg[r], il);
                #pragma unroll
                for (int cc = 0; cc < 7; ++cc) A1[r][cc] = fmaf(x, wv[cc], A1[r][cc]);
            }
        }
        #pragma unroll
        for (int cc = 0; cc < 7; ++cc) {
            const float bb = b1[jm[cc]];
            #pragma unroll
            for (int r = 0; r < 8; ++r) A1[r][cc] = fmaxf(A1[r][cc] + bb, 0.f);
        }
    }

    // ---- layer 2: 400 -> 400 (relu), A1 -> A2 ----
    {
        #pragma unroll
        for (int r = 0; r < 8; ++r)
            #pragma unroll
            for (int cc = 0; cc < 7; ++cc) A2[r][cc] = 0.f;
        #pragma unroll
        for (int cs = 0; cs < 7; ++cs) {
            const int ilim = (cs == 6) ? 16 : 64;
            #pragma unroll 4
            for (int il = 0; il < ilim; ++il) {
                const int i = cs*64 + il;
                float wv[7];
                #pragma unroll
                for (int cc = 0; cc < 7; ++cc) wv[cc] = W2[i*400 + jm[cc]];
                #pragma unroll
                for (int r = 0; r < 8; ++r) {
                    const float x = rdlane(A1[r][cs], il);
                    #pragma unroll
                    for (int cc = 0; cc < 7; ++cc) A2[r][cc] = fmaf(x, wv[cc], A2[r][cc]);
                }
            }
        }
        #pragma unroll
        for (int cc = 0; cc < 7; ++cc) {
            const float bb = b2[jm[cc]];
            #pragma unroll
            for (int r = 0; r < 8; ++r) A2[r][cc] = fmaxf(A2[r][cc] + bb, 0.f);
        }
    }

    // ---- layer 3: 400 -> 400 (relu), A2 -> A1 ----
    {
        #pragma unroll
        for (int r = 0; r < 8; ++r)
            #pragma unroll
            for (int cc = 0; cc < 7; ++cc) A1[r][cc] = 0.f;
        #pragma unroll
        for (int cs = 0; cs < 7; ++cs) {
            const int ilim = (cs == 6) ? 16 : 64;
            #pragma unroll 4
            for (int il = 0; il < ilim; ++il) {
                const int i = cs*64 + il;
                float wv[7];
                #pragma unroll
                for (int cc = 0; cc < 7; ++cc) wv[cc] = W3[i*400 + jm[cc]];
                #pragma unroll
                for (int r = 0; r < 8; ++r) {
                    const float x = rdlane(A2[r][cs], il);
                    #pragma unroll
                    for (int cc = 0; cc < 7; ++cc) A1[r][cc] = fmaf(x, wv[cc], A1[r][cc]);
                }
            }
        }
        #pragma unroll
        for (int cc = 0; cc < 7; ++cc) {
            const float bb = b3[jm[cc]];
            #pragma unroll
            for (int r = 0; r < 8; ++r) A1[r][cc] = fmaxf(A1[r][cc] + bb, 0.f);
        }
    }

    // ---- layer 4: 400 -> 128 (no relu), A1 -> acc4 (lane t: cols t, 64+t) ----
    float acc4[8][2];
    {
        #pragma unroll
        for (int r = 0; r < 8; ++r) { acc4[r][0] = 0.f; acc4[r][1] = 0.f; }
        #pragma unroll
        for (int cs = 0; cs < 7; ++cs) {
            const int ilim = (cs == 6) ? 16 : 64;
            #pragma unroll 4
            for (int il = 0; il < ilim; ++il) {
                const int i = cs*64 + il;
                const float w0 = W4[i*128 + t];
                const float w1 = W4[i*128 + 64 + t];
                #pragma unroll
                for (int r = 0; r < 8; ++r) {
                    const float x = rdlane(A1[r][cs], il);
                    acc4[r][0] = fmaf(x, w0, acc4[r][0]);
                    acc4[r][1] = fmaf(x, w1, acc4[r][1]);
                }
            }
        }
        const float bb0 = b4[t], bb1 = b4[64 + t];
        #pragma unroll
        for (int r = 0; r < 8; ++r) { acc4[r][0] += bb0; acc4[r][1] += bb1; }
    }

    // ---- LayerNorm over 128 (values spread: 2/lane x 64 lanes) ----
    float lnv[8][2];
    {
        const float* g  = half ? g_k : g_q;
        const float* be = half ? beta_k : beta_q;
        const float gl0 = g[t],  gl1 = g[64 + t];
        const float bl0 = be[t], bl1 = be[64 + t];
        #pragma unroll
        for (int r = 0; r < 8; ++r) {
            float s = acc4[r][0] + acc4[r][1];
            #pragma unroll
            for (int o = 32; o > 0; o >>= 1) s += __shfl_xor(s, o);
            const float mu = s * (1.f/128.f);
            const float d0 = acc4[r][0] - mu, d1 = acc4[r][1] - mu;
            float vs = d0*d0 + d1*d1;
            #pragma unroll
            for (int o = 32; o > 0; o >>= 1) vs += __shfl_xor(vs, o);
            const float rstd = rsqrtf(vs * (1.f/128.f) + 1e-5f);
            lnv[r][0] = d0*rstd*gl0 + bl0;
            lnv[r][1] = d1*rstd*gl1 + bl1;
        }
    }

    // ---- projection 128 -> 512 (8 cols/lane), write fp32 (+bf16-hi for k) ----
    {
        const float* Wp = half ? Wk : Wq;
        const float* bp = half ? bk : bq;
        float* of = half ? kf : qf;
        float accp[8][8];
        #pragma unroll
        for (int r = 0; r < 8; ++r)
            #pragma unroll
            for (int cc = 0; cc < 8; ++cc) accp[r][cc] = 0.f;
        #pragma unroll
        for (int cs = 0; cs < 2; ++cs) {
            #pragma unroll 4
            for (int il = 0; il < 64; ++il) {
                const int i = cs*64 + il;
                float wv[8];
                #pragma unroll
                for (int cc = 0; cc < 8; ++cc) wv[cc] = Wp[i*512 + cc*64 + t];
                #pragma unroll
                for (int r = 0; r < 8; ++r) {
                    const float x = rdlane(lnv[r][cs], il);
                    #pragma unroll
                    for (int cc = 0; cc < 8; ++cc) accp[r][cc] = fmaf(x, wv[cc], accp[r][cc]);
                }
            }
        }
        float bpv[8];
        #pragma unroll
        for (int cc = 0; cc < 8; ++cc) bpv[cc] = bp[cc*64 + t];
        #pragma unroll
        for (int r = 0; r < 8; ++r) {
            const int gidx = rbase + r;
            const int bb = gidx >> 11, s = gidx & 2047;
            #pragma unroll
            for (int cc = 0; cc < 8; ++cc) {
                const int j  = cc*64 + t;
                const int hh = j >> 7, d = j & 127;
                const float v = accp[r][cc] + bpv[cc];
                const size_t dst = ((size_t)(bb*4 + hh)*2048 + s)*128 + d;
                of[dst] = v;
                if (half) khi[dst] = __float2bfloat16(v);
            }
        }
    }
}

// ---------------------------------------------------------------------------
// Kernel B: MFMA scan over an m-quarter (512 cols) + branchless per-quad
// register top-20 + per-row owner merge -> approx-top-24 keys to ws.
// Block = (stile, hb, mq). Lane (w,m16,quad) owns q-row stile*64+w*16+m16;
// quad covers cols colb+quad*4+reg. Keys: (mono(score)&~0x7FF)|col.
// ---------------------------------------------------------------------------
__global__ __launch_bounds__(256) void k_scan(
    const float* __restrict__ qf, const __hip_bfloat16* __restrict__ khi,
    unsigned* __restrict__ wsk)
{
    __shared__ unsigned kd[64*4*21];   // 21.5KB lane-list dump (pad 21)

    const int tid   = threadIdx.x;
    const int stile = blockIdx.x;      // 0..31
    const int hb    = blockIdx.y;      // 0..15
    const int mq    = blockIdx.z;      // 0..3

    const int lane = tid & 63;
    const int w    = tid >> 6;
    const int m16  = lane & 15;
    const int quad = lane >> 4;

    const size_t slab = (size_t)hb * 2048;
    const __hip_bfloat16* slabp = khi + slab*128;

    const int sg_my = stile*64 + w*16 + m16;

    // Q fragment (B operand): B[n=m16][k=quad*8+j+ks*32] = q[w*16+n][k]
    short8v bq_[4];
    {
        const float* qp = qf + (slab + sg_my)*128 + quad*8;
        #pragma unroll
        for (int ks = 0; ks < 4; ++ks) {
            const float4 x0 = *(const float4*)(qp + ks*32);
            const float4 x1 = *(const float4*)(qp + ks*32 + 4);
            short8v tt;
            tt[0]=f2bf_s(x0.x); tt[1]=f2bf_s(x0.y); tt[2]=f2bf_s(x0.z); tt[3]=f2bf_s(x0.w);
            tt[4]=f2bf_s(x1.x); tt[5]=f2bf_s(x1.y); tt[6]=f2bf_s(x1.z); tt[7]=f2bf_s(x1.w);
            bq_[ks] = tt;
        }
    }

    unsigned keys[20];                 // ascending; keys[0] = min
    #pragma unroll
    for (int n = 0; n < 20; ++n) keys[n] = 0u;

    #pragma unroll 2
    for (int l = 0; l < 8; ++l) {
        const int mt = mq*8 + l;
        #pragma unroll
        for (int ct = 0; ct < 4; ++ct) {
            const int colb = mt*64 + ct*16;
            const __hip_bfloat16* kp = slabp + (size_t)(colb + m16)*128 + quad*8;
            float4v acc = (float4v){0.f,0.f,0.f,0.f};
            #pragma unroll
            for (int ks = 0; ks < 4; ++ks) {
                const short8v ka = *(const short8v*)(kp + ks*32);
                acc = __builtin_amdgcn_mfma_f32_16x16x32_bf16(ka, bq_[ks], acc, 0, 0, 0);
            }
            const int cb = colb + quad*4;
            #pragma unroll
            for (int reg = 0; reg < 4; ++reg) {
                const int m = cb + reg;
                unsigned key = (mono(acc[reg]) & 0xFFFFF800u) | (unsigned)m;
                key = (m == sg_my) ? 0u : key;              // diagonal excluded
                keys[0] = (key > keys[0]) ? key : keys[0];  // drop-min insert
                #pragma unroll
                for (int i = 0; i < 19; ++i) {              // bubble restores order
                    const unsigned a = keys[i], c = keys[i+1];
                    keys[i]   = (a < c) ? a : c;
                    keys[i+1] = (a < c) ? c : a;
                }
            }
        }
    }

    // dump descending per (row, quad)
    const int rr = w*16 + m16;
    #pragma unroll
    for (int n = 0; n < 20; ++n)
        kd[(rr*4 + quad)*21 + n] = keys[19 - n];
    __syncthreads();

    // owner (quad 0): merge 4 sorted-desc 20-lists -> top-24 -> ws (desc)
    if (quad == 0) {
        const unsigned* L0 = &kd[(rr*4 + 0)*21];
        const unsigned* L1 = &kd[(rr*4 + 1)*21];
        const unsigned* L2 = &kd[(rr*4 + 2)*21];
        const unsigned* L3 = &kd[(rr*4 + 3)*21];
        int p0 = 0, p1 = 0, p2 = 0, p3 = 0;
        const size_t base = (size_t)hb*2048 + stile*64 + rr;
        for (int n = 0; n < 24; ++n) {
            const unsigned h0 = (p0 < 20) ? L0[p0] : 0u;
            const unsigned h1 = (p1 < 20) ? L1[p1] : 0u;
            const unsigned h2 = (p2 < 20) ? L2[p2] : 0u;
            const unsigned h3 = (p3 < 20) ? L3[p3] : 0u;
            unsigned bv = h0; int bs = 0;
            if (h1 > bv) { bv = h1; bs = 1; }
            if (h2 > bv) { bv = h2; bs = 2; }
            if (h3 > bv) { bv = h3; bs = 3; }
            if (bs == 0) ++p0; else if (bs == 1) ++p1; else if (bs == 2) ++p2; else ++p3;
            wsk[(size_t)(mq*24 + n)*32768 + base] = bv;
        }
    }
}

// ---------------------------------------------------------------------------
// Kernel C: per row merge 4x24 approx keys -> top-32 -> cooperative exact
// fp32 rescore (4 lanes/row, coalesced segments, butterfly reduce) -> exact
// top-20 -> quantiles + outputs + score accumulation.
// Block = (stile, hb), 64 rows.
// ---------------------------------------------------------------------------
__global__ __launch_bounds__(256) void k_select(
    const float* __restrict__ qf, const float* __restrict__ kf,
    const unsigned* __restrict__ wsk,
    const float* __restrict__ errors, const float* __restrict__ y,
    const float* __restrict__ y_pred,
    float* __restrict__ out, float* __restrict__ hacc)
{
    __shared__ unsigned kd[64*4*25];       // 25.6KB (pad 25)
    __shared__ unsigned short cb[64*33];   // 4.2KB candidate cols
    __shared__ float es[64*33];            // 8.4KB exact scores
    __shared__ float ebuf[64*21];          // 5.4KB sort buffer

    const int tid   = threadIdx.x;
    const int stile = blockIdx.x;          // 0..31
    const int hb    = blockIdx.y;          // 0..15
    const int b     = hb >> 2;
    const int h     = hb & 3;

    const int lane = tid & 63;
    const int w    = tid >> 6;
    const int m16  = lane & 15;
    const int quad = lane >> 4;
    const int rr   = w*16 + m16;
    const int sg   = stile*64 + rr;

    const size_t base = (size_t)hb*2048 + sg;
    // lane loads mq=quad's 24 keys (coalesced across rows)
    #pragma unroll 4
    for (int n = 0; n < 24; ++n)
        kd[(rr*4 + quad)*25 + n] = wsk[(size_t)(quad*24 + n)*32768 + base];
    __syncthreads();

    // owner: merge 4 sorted-desc 24-lists -> approx-top-32 cols
    if (quad == 0) {
        const unsigned* L0 = &kd[(rr*4 + 0)*25];
        const unsigned* L1 = &kd[(rr*4 + 1)*25];
        const unsigned* L2 = &kd[(rr*4 + 2)*25];
        const unsigned* L3 = &kd[(rr*4 + 3)*25];
        int p0 = 0, p1 = 0, p2 = 0, p3 = 0;
        for (int n = 0; n < 32; ++n) {
            const unsigned h0 = (p0 < 24) ? L0[p0] : 0u;
            const unsigned h1 = (p1 < 24) ? L1[p1] : 0u;
            const unsigned h2 = (p2 < 24) ? L2[p2] : 0u;
            const unsigned h3 = (p3 < 24) ? L3[p3] : 0u;
            unsigned bv = h0; int bs = 0;
            if (h1 > bv) { bv = h1; bs = 1; }
            if (h2 > bv) { bv = h2; bs = 2; }
            if (h3 > bv) { bv = h3; bs = 3; }
            if (bs == 0) ++p0; else if (bs == 1) ++p1; else if (bs == 2) ++p2; else ++p3;
            cb[rr*33 + n] = (unsigned short)(bv & 0x7FFu);
        }
    }
    __syncthreads();

    // cooperative exact rescore of the 32 candidates
    const size_t slab = (size_t)hb * 2048;
    const float* qrow_p = qf + (slab + sg)*128;
    float4 qseg[8];
    #pragma unroll
    for (int u = 0; u < 8; ++u)
        qseg[u] = *(const float4*)(qrow_p + quad*4 + u*16);
    const float* kslab = kf + slab*128;
    #pragma unroll 2
    for (int n = 0; n < 32; ++n) {
        const int col = cb[rr*33 + n];
        const float* kc = kslab + (size_t)col*128 + quad*4;
        float4v s = (float4v){0.f,0.f,0.f,0.f};
        #pragma unroll
        for (int u = 0; u < 8; ++u) {
            const float4 kv = *(const float4*)(kc + u*16);
            s[0] = fmaf(qseg[u].x, kv.x, s[0]);
            s[1] = fmaf(qseg[u].y, kv.y, s[1]);
            s[2] = fmaf(qseg[u].z, kv.z, s[2]);
            s[3] = fmaf(qseg[u].w, kv.w, s[3]);
        }
        float v = (s[0] + s[1]) + (s[2] + s[3]);
        v += __shfl_xor(v, 16);
        v += __shfl_xor(v, 32);
        if (quad == 0) es[rr*33 + n] = v;
    }

    // owner: exact top-20 selection (desc, col asc ties) + quantiles
    float sq = 0.f;
    if (quad == 0) {
        float* e = &ebuf[rr*21];
        for (int k = 0; k < 20; ++k) {
            float best = -INFINITY; int bc = 4096, bj = 0;
            for (int j = 0; j < 32; ++j) {
                const float v = es[rr*33 + j];
                const int c = cb[rr*33 + j];
                if (v > best || (v == best && c < bc)) { best = v; bc = c; bj = j; }
            }
            es[rr*33 + bj] = -INFINITY;
            e[k] = errors[((size_t)(b*SS + bc))*4];   // errors[..., 0]
        }
        for (int a = 1; a < 20; ++a) {     // insertion sort ascending
            const float v = e[a];
            int n = a;
            while (n > 0 && e[n-1] > v) { e[n] = e[n-1]; --n; }
            e[n] = v;
        }
        const float yp = y_pred[((size_t)(b*SS + sg))*4];
        const float yt = y[((size_t)(b*SS + sg))*4];
        float msum = 0.f;
        const size_t obase = ((size_t)(h*4 + b)*18)*2048 + sg;
        #pragma unroll 1
        for (int a = 0; a < 18; ++a) {
            const float alpha = c_alphas[a];
            const float beta  = 0.5f*alpha;
            const float pl = beta * 19.f;
            const int   il = (int)pl;
            const float fl = pl - (float)il;
            const float ql = e[il]*(1.f-fl) + e[il+1]*fl;
            const float qq = (1.f - alpha) + beta;
            const float ph = qq * 19.f;
            const int   ih = (int)ph;
            const float fh = ph - (float)ih;
            const float qh = e[ih]*(1.f-fh) + e[ih+1]*fh;
            msum += ql + qh;
            const size_t oidx = obase + (size_t)a*2048;
            out[OFF_YLOW  + oidx] = ql + yp;
            out[OFF_YHIGH + oidx] = qh + yp;
            out[OFF_QLOW  + oidx] = ql;
            out[OFF_QHIGH + oidx] = qh;
        }
        const float me = msum * (1.f/36.f);
        const float dd = yt - (me + yp);
        sq = dd*dd;
    }
    // wave-reduce sq (non-owners contribute 0), one atomic per wave
    #pragma unroll
    for (int o = 32; o > 0; o >>= 1) sq += __shfl_xor(sq, o);
    if (lane == 0) atomicAdd(&hacc[h], sq);
}

__global__ void k_init(float* __restrict__ hacc) {
    if (threadIdx.x < 4) hacc[threadIdx.x] = 0.f;
}

__global__ __launch_bounds__(256) void k_finalize(
    const float* __restrict__ y, const float* __restrict__ y_pred,
    const float* __restrict__ errors, const float* __restrict__ hacc,
    float* __restrict__ out)
{
    const int i = blockIdx.x*256 + threadIdx.x;
    if (i == 0)
        out[0] = (hacc[0]+hacc[1]+hacc[2]+hacc[3]) * (1.f/32768.f);
    if (i < 32768)      out[OFF_Y + i] = y[i];
    else if (i < 65536) out[OFF_YPRED + (i - 32768)] = y_pred[i - 32768];
    else if (i < 73728) { const int j = i - 65536; out[OFF_ERR + j] = errors[(size_t)j*4]; }
}

extern "C" void kernel_launch(void* const* d_in, const int* in_sizes, int n_in,
                              void* d_out, int out_size, void* d_ws, size_t ws_size,
                              hipStream_t stream)
{
    const float* Xt     = (const float*)d_in[0];
    const float* Xs     = (const float*)d_in[1];
    const float* errors = (const float*)d_in[2];
    const float* y      = (const float*)d_in[3];
    const float* y_pred = (const float*)d_in[4];
    const float* W1 = (const float*)d_in[5];   const float* b1 = (const float*)d_in[6];
    const float* W2 = (const float*)d_in[7];   const float* b2 = (const float*)d_in[8];
    const float* W3 = (const float*)d_in[9];   const float* b3 = (const float*)d_in[10];
    const float* W4 = (const float*)d_in[11];  const float* b4 = (const float*)d_in[12];
    const float* Wq = (const float*)d_in[13];  const float* bq = (const float*)d_in[14];
    const float* Wk = (const float*)d_in[15];  const float* bk = (const float*)d_in[16];
    const float* g_q    = (const float*)d_in[17];
    const float* beta_q = (const float*)d_in[18];
    const float* g_k    = (const float*)d_in[19];
    const float* beta_k = (const float*)d_in[20];

    float* out  = (float*)d_out;
    char*  base = (char*)d_ws;
    const size_t SLAB = (size_t)16*2048*128;               // 4,194,304 elements
    float* hacc = (float*)base;                            // 64B slot
    float* qf   = (float*)(base + 256);                    // 16MB
    float* kf   = qf + SLAB;                               // 16MB
    __hip_bfloat16* khi = (__hip_bfloat16*)(kf + SLAB);    // 8MB
    unsigned* wsk = (unsigned*)(khi + SLAB);               // 4*24*32768 u32 = 12.6MB

    k_init<<<1, 64, 0, stream>>>(hacc);
    k_mlp<<<2048, 64, 0, stream>>>(Xt, Xs, W1,b1,W2,b2,W3,b3,W4,b4,
                                   Wq,bq,Wk,bk,g_q,beta_q,g_k,beta_k,
                                   qf, kf, khi);
    k_scan<<<dim3(32,16,4), 256, 0, stream>>>(qf, khi, wsk);
    k_select<<<dim3(32,16), 256, 0, stream>>>(qf, kf, wsk, errors, y, y_pred, out, hacc);
    k_finalize<<<288, 256, 0, stream>>>(y, y_pred, errors, hacc, out);
}